// Round 1
// baseline (123.307 us; speedup 1.0000x reference)
//
#include <hip/hip_runtime.h>
#include <stdint.h>

// YOLO loss: pred (B,30,7,7) f32, label (B,30,7,7) f32 -> scalar f32 (sum/B).
// Memory-bound: 96.3 MB read once -> 15.3 us floor @6.3 TB/s (cold: harness
// flushes L3 with 2x256MiB poison fills, ~82 us fixed cost inside the timed graph).
//
// R5: previous kernel (512x512 grid-stride, 60 scalar dword loads/thread) is
// inferred at ~30 us (dur 115.2 - 2 fills @40.7 - memset). Theory: issue/latency
// bound, not BW bound. This version stages 4 batch items/block into LDS with
// __builtin_amdgcn_global_load_lds width=16 (12 linear 1KiB/wave loads, no VGPR
// round-trip), 3 blocks/CU co-resident so one block's vmcnt(0)+barrier drain is
// hidden under the others' compute. Compute math is copied verbatim from the
// verified R4 kernel; only the data path changed.

constexpr int NT    = 256;                       // threads/block (4 waves)
constexpr int ITEMS = 4;                         // batch items per block
constexpr int FL_PER_ITEM = 1470;                // 30*7*7 floats per item
constexpr int NF4   = ITEMS * FL_PER_ITEM / 4;   // 1470 float4 per array
constexpr int NROUND = (NF4 + NT - 1) / NT;      // 6 staging rounds
constexpr int NF4_PAD = NROUND * NT;             // 1536 (pad keeps lds dest linear)

__device__ __forceinline__ float sq(float x) { return x * x; }

__device__ __forceinline__ void g2lds16(const void* g, void* l) {
    __builtin_amdgcn_global_load_lds(
        (const __attribute__((address_space(1))) void*)g,
        (__attribute__((address_space(3))) void*)l,
        16, 0, 0);
}

__global__ __launch_bounds__(NT) void yolo_loss_kernel(
    const float* __restrict__ pred, const float* __restrict__ label,
    float* __restrict__ out, int B, float inv_B)
{
    __shared__ float sp[NF4_PAD * 4];     // 24576 B
    __shared__ float sl[NF4_PAD * 4];     // 24576 B  -> 49 KB total, 3 blocks/CU
    __shared__ float swave[NT / 64];

    const int tid = threadIdx.x;
    const int b0  = blockIdx.x * ITEMS;
    const int items = min(ITEMS, B - b0);

    if (items == ITEMS) {
        // fast path: 16B-aligned (b0*5880 B, b0 multiple of 4 -> %16==0),
        // fully linear global->LDS DMA. Dest is wave-uniform base + lane*16
        // by construction; clamp only the (per-lane) SOURCE for pad slots.
        const char* pg = (const char*)pred  + (size_t)b0 * (FL_PER_ITEM * 4);
        const char* lg = (const char*)label + (size_t)b0 * (FL_PER_ITEM * 4);
#pragma unroll
        for (int k = 0; k < NROUND; ++k) {
            int t  = k * NT + tid;
            int tc = t < NF4 ? t : NF4 - 1;   // dup-read pad slots (harmless)
            g2lds16(pg + (size_t)tc * 16, (char*)sp + (size_t)t * 16);
            g2lds16(lg + (size_t)tc * 16, (char*)sl + (size_t)t * 16);
        }
    } else {
        // tail block (not hit for B % ITEMS == 0) — scalar staging
        const float* pg = pred  + (size_t)b0 * FL_PER_ITEM;
        const float* lg = label + (size_t)b0 * FL_PER_ITEM;
        for (int t = tid; t < items * FL_PER_ITEM; t += NT) {
            sp[t] = pg[t];
            sl[t] = lg[t];
        }
    }
    __syncthreads();   // drains vmcnt(0) -> global_load_lds complete

    const float Gc = 1.0f / 7.0f;
    float acc = 0.0f;

    for (int t = tid; t < items * 49; t += NT) {   // 196 cells, tid<196 active
        int k = t / 49;
        int s = t - k * 49;
        int i = s / 7;          // axis 2, paired with x
        int j = s - i * 7;      // axis 3, paired with y
        const float* P = sp + k * FL_PER_ITEM + s;
        const float* L = sl + k * FL_PER_ITEM + s;

        float p[30], l[30];
#pragma unroll
        for (int c = 0; c < 30; ++c) {
            p[c] = P[c * 49];   // ds_read_b32, imm offsets, stride-1 lanes: no conflicts
            l[c] = L[c * 49];
        }

        float fi = (float)i, fj = (float)j;

        // box 1 (pred ch 0..3)
        float cx1 = (p[0] + fi) * Gc, cy1 = (p[1] + fj) * Gc;
        float a_x1 = cx1 - p[2] * 0.5f, a_y1 = cy1 - p[3] * 0.5f;
        float a_x2 = cx1 + p[2] * 0.5f, a_y2 = cy1 + p[3] * 0.5f;
        // box 2 (pred ch 5..8)
        float cx2 = (p[5] + fi) * Gc, cy2 = (p[6] + fj) * Gc;
        float b_x1 = cx2 - p[7] * 0.5f, b_y1 = cy2 - p[8] * 0.5f;
        float b_x2 = cx2 + p[7] * 0.5f, b_y2 = cy2 + p[8] * 0.5f;
        // degenerate label point-box
        float lx = (l[0] + fi) * Gc - l[2] * 0.5f;
        float ly = (l[1] + fj) * Gc - l[3] * 0.5f;

        // iou(box, point-box) — faithful to reference (area_b = 0)
        auto iou_pt = [&](float x1, float y1, float x2, float y2) {
            float ix = fminf(x2, lx) - fmaxf(x1, lx);
            float iy = fminf(y2, ly) - fmaxf(y1, ly);
            float inter = fmaxf(ix, 0.0f) * fmaxf(iy, 0.0f);
            float area_a = (x2 - x1) * (y2 - y1);
            float uni = area_a + 0.0f - inter;
            float denom = (uni == 0.0f) ? 1.0f : uni;
            return inter / denom;
        };

        float iou1 = iou_pt(a_x1, a_y1, a_x2, a_y2);
        float iou2 = iou_pt(b_x1, b_y1, b_x2, b_y2);
        bool sel1 = iou1 > iou2;

        float t1 = sq(p[0] - l[0]) + sq(p[1] - l[1])
                 + sq(sqrtf(p[2]) - sqrtf(l[2])) + sq(sqrtf(p[3]) - sqrtf(l[3]));
        float t2 = sq(p[5] - l[5]) + sq(p[6] - l[6])
                 + sq(sqrtf(p[7]) - sqrtf(l[7])) + sq(sqrtf(p[8]) - sqrtf(l[8]));

        float obj_term     = sel1 ? t1 : t2;
        float conf_term    = sel1 ? sq(p[4] - 1.0f) : sq(p[9] - 1.0f);
        float noobj_obj    = sel1 ? sq(p[9]) : sq(p[4]);
        float noobj_empty  = sq(p[4]) + sq(p[9]);

        float cls = 0.0f;
#pragma unroll
        for (int c = 10; c < 30; ++c) cls += sq(p[c] - l[c]);

        bool obj = (l[4] == 1.0f);
        // obj_weight = 0.5, noobj_weight = 0.5
        acc += obj ? (0.5f * obj_term + conf_term + cls + 0.5f * noobj_obj)
                   : (0.5f * noobj_empty);
    }

    // wave (64-lane) shuffle reduce
#pragma unroll
    for (int off = 32; off > 0; off >>= 1)
        acc += __shfl_down(acc, off, 64);

    int lane = threadIdx.x & 63;
    int wid  = threadIdx.x >> 6;
    if (lane == 0) swave[wid] = acc;
    __syncthreads();
    if (threadIdx.x == 0) {
        float bs = 0.0f;
#pragma unroll
        for (int w = 0; w < NT / 64; ++w) bs += swave[w];
        atomicAdd(out, bs * inv_B);   // 2048 fire-and-forget atomics, staggered
    }
}

extern "C" void kernel_launch(void* const* d_in, const int* in_sizes, int n_in,
                              void* d_out, int out_size, void* d_ws, size_t ws_size,
                              hipStream_t stream) {
    const float* pred  = (const float*)d_in[0];
    const float* label = (const float*)d_in[1];
    float* out = (float*)d_out;

    int B = in_sizes[0] / 1470;
    int NB = (B + ITEMS - 1) / ITEMS;   // 2048 for B=8192

    hipMemsetAsync(d_out, 0, sizeof(float), stream);

    yolo_loss_kernel<<<NB, NT, 0, stream>>>(pred, label, out, B,
                                            1.0f / (float)B);
}